// Round 1
// baseline (3693.000 us; speedup 1.0000x reference)
//
#include <hip/hip_runtime.h>

#define HH 50   // hidden size
#define HP 64   // padded hidden (lanes)
#define RB 8    // batch elements per block
#define TT 512  // timesteps
#define FF 4    // input features

__device__ __forceinline__ float sigm(float x)   { return 1.0f / (1.0f + __expf(-x)); }
__device__ __forceinline__ float tanh_f(float x) { return 1.0f - 2.0f / (1.0f + __expf(2.0f * x)); }

__launch_bounds__(256, 2)
__global__ void lstm2_kernel(const float* __restrict__ x,
                             const float* __restrict__ Wih0, const float* __restrict__ Whh0,
                             const float* __restrict__ bih0, const float* __restrict__ bhh0,
                             const float* __restrict__ Wih1, const float* __restrict__ Whh1,
                             const float* __restrict__ bih1, const float* __restrict__ bhh1,
                             const float* __restrict__ fcW,  const float* __restrict__ fcb,
                             float* __restrict__ out)
{
    // LDS: h-state broadcast buffers ([unit][batch], float4-readable),
    // gate exchange buffer ([gate][batch][unit], stride-1 lanes), x chunk cache.
    __shared__ __align__(16) float h0buf[HP][RB];
    __shared__ __align__(16) float h1buf[HP][RB];
    __shared__ float gbuf[4][RB][HP];
    __shared__ __align__(16) float4 xbuf[64][RB];

    const int tid = threadIdx.x;
    const int w   = tid >> 6;   // wave id = gate type (0=i,1=f,2=g,3=o)
    const int U   = tid & 63;   // lane = hidden unit (active if < 50)
    const int b0  = blockIdx.x * RB;
    const bool on = (U < HH);
    const int row = w * HH + (on ? U : 0);   // gate row in [0,200)

    // zero h state
    for (int i = tid; i < HP * RB; i += 256) {
        (&h0buf[0][0])[i] = 0.0f;
        (&h1buf[0][0])[i] = 0.0f;
    }

    // load all weights into registers (time-invariant, reused 512x)
    float wih0[FF], whh0[HH], wih1[HH], whh1[HH];
    #pragma unroll
    for (int j = 0; j < FF; j++) wih0[j] = on ? Wih0[row * FF + j] : 0.0f;
    #pragma unroll
    for (int j = 0; j < HH; j++) whh0[j] = on ? Whh0[row * HH + j] : 0.0f;
    #pragma unroll
    for (int j = 0; j < HH; j++) wih1[j] = on ? Wih1[row * HH + j] : 0.0f;
    #pragma unroll
    for (int j = 0; j < HH; j++) whh1[j] = on ? Whh1[row * HH + j] : 0.0f;
    const float bias0 = on ? (bih0[row] + bhh0[row]) : 0.0f;
    const float bias1 = on ? (bih1[row] + bhh1[row]) : 0.0f;

    // elementwise r-slice owned by this wave
    const int r0 = 2 * w, r1 = 2 * w + 1;
    float c0a = 0.0f, c0b = 0.0f, c1a = 0.0f, c1b = 0.0f;

    __syncthreads();

    for (int t = 0; t < TT; t++) {
        // stage a 64-timestep chunk of x into LDS
        if ((t & 63) == 0) {
            __syncthreads();
            #pragma unroll
            for (int it = 0; it < 2; it++) {
                const int q  = tid + it * 256;          // [0,512)
                const int r  = q >> 6;
                const int tl = q & 63;
                xbuf[tl][r] = *(const float4*)(x + ((size_t)(b0 + r) * TT + (t + tl)) * FF);
            }
            __syncthreads();
        }

        float acc[RB];

        // ---------- layer 0 gates ----------
        #pragma unroll
        for (int r = 0; r < RB; r++) {
            const float4 xv = xbuf[t & 63][r];
            acc[r] = bias0 + wih0[0] * xv.x + wih0[1] * xv.y + wih0[2] * xv.z + wih0[3] * xv.w;
        }
        #pragma unroll
        for (int j = 0; j < HH; j++) {
            const float wj = whh0[j];
            const float4 ha = *(const float4*)&h0buf[j][0];
            const float4 hb = *(const float4*)&h0buf[j][4];
            acc[0] = fmaf(wj, ha.x, acc[0]);
            acc[1] = fmaf(wj, ha.y, acc[1]);
            acc[2] = fmaf(wj, ha.z, acc[2]);
            acc[3] = fmaf(wj, ha.w, acc[3]);
            acc[4] = fmaf(wj, hb.x, acc[4]);
            acc[5] = fmaf(wj, hb.y, acc[5]);
            acc[6] = fmaf(wj, hb.z, acc[6]);
            acc[7] = fmaf(wj, hb.w, acc[7]);
        }
        if (w == 2) {
            #pragma unroll
            for (int r = 0; r < RB; r++) gbuf[w][r][U] = tanh_f(acc[r]);
        } else {
            #pragma unroll
            for (int r = 0; r < RB; r++) gbuf[w][r][U] = sigm(acc[r]);
        }
        __syncthreads();

        // ---------- layer 0 elementwise (this wave owns r0, r1) ----------
        {
            const float i0 = gbuf[0][r0][U], f0 = gbuf[1][r0][U], g0 = gbuf[2][r0][U], o0 = gbuf[3][r0][U];
            c0a = fmaf(f0, c0a, i0 * g0);
            h0buf[U][r0] = o0 * tanh_f(c0a);
            const float i1 = gbuf[0][r1][U], f1 = gbuf[1][r1][U], g1 = gbuf[2][r1][U], o1 = gbuf[3][r1][U];
            c0b = fmaf(f1, c0b, i1 * g1);
            h0buf[U][r1] = o1 * tanh_f(c0b);
        }
        __syncthreads();

        // ---------- layer 1 gates ----------
        #pragma unroll
        for (int r = 0; r < RB; r++) acc[r] = bias1;
        #pragma unroll
        for (int j = 0; j < HH; j++) {
            const float wi = wih1[j];
            const float wh = whh1[j];
            const float4 pa = *(const float4*)&h0buf[j][0];
            const float4 pb = *(const float4*)&h0buf[j][4];
            const float4 qa = *(const float4*)&h1buf[j][0];
            const float4 qb = *(const float4*)&h1buf[j][4];
            acc[0] = fmaf(wi, pa.x, fmaf(wh, qa.x, acc[0]));
            acc[1] = fmaf(wi, pa.y, fmaf(wh, qa.y, acc[1]));
            acc[2] = fmaf(wi, pa.z, fmaf(wh, qa.z, acc[2]));
            acc[3] = fmaf(wi, pa.w, fmaf(wh, qa.w, acc[3]));
            acc[4] = fmaf(wi, pb.x, fmaf(wh, qb.x, acc[4]));
            acc[5] = fmaf(wi, pb.y, fmaf(wh, qb.y, acc[5]));
            acc[6] = fmaf(wi, pb.z, fmaf(wh, qb.z, acc[6]));
            acc[7] = fmaf(wi, pb.w, fmaf(wh, qb.w, acc[7]));
        }
        if (w == 2) {
            #pragma unroll
            for (int r = 0; r < RB; r++) gbuf[w][r][U] = tanh_f(acc[r]);
        } else {
            #pragma unroll
            for (int r = 0; r < RB; r++) gbuf[w][r][U] = sigm(acc[r]);
        }
        __syncthreads();

        // ---------- layer 1 elementwise ----------
        {
            const float i0 = gbuf[0][r0][U], f0 = gbuf[1][r0][U], g0 = gbuf[2][r0][U], o0 = gbuf[3][r0][U];
            c1a = fmaf(f0, c1a, i0 * g0);
            h1buf[U][r0] = o0 * tanh_f(c1a);
            const float i1 = gbuf[0][r1][U], f1 = gbuf[1][r1][U], g1 = gbuf[2][r1][U], o1 = gbuf[3][r1][U];
            c1b = fmaf(f1, c1b, i1 * g1);
            h1buf[U][r1] = o1 * tanh_f(c1b);
        }
        __syncthreads();
    }

    // ---------- final FC: out[b] = fcW @ h1_T + fcb ----------
    if (tid < 32) {
        const int r  = tid >> 2;
        const int ft = tid & 3;
        float s = fcb[ft];
        #pragma unroll
        for (int j = 0; j < HH; j++) s = fmaf(fcW[ft * HH + j], h1buf[j][r], s);
        out[(size_t)(b0 + r) * FF + ft] = s;
    }
}

extern "C" void kernel_launch(void* const* d_in, const int* in_sizes, int n_in,
                              void* d_out, int out_size, void* d_ws, size_t ws_size,
                              hipStream_t stream) {
    const float* x    = (const float*)d_in[0];
    const float* Wih0 = (const float*)d_in[1];
    const float* Whh0 = (const float*)d_in[2];
    const float* bih0 = (const float*)d_in[3];
    const float* bhh0 = (const float*)d_in[4];
    const float* Wih1 = (const float*)d_in[5];
    const float* Whh1 = (const float*)d_in[6];
    const float* bih1 = (const float*)d_in[7];
    const float* bhh1 = (const float*)d_in[8];
    const float* fcW  = (const float*)d_in[9];
    const float* fcb  = (const float*)d_in[10];
    float* out = (float*)d_out;

    const int B = in_sizes[0] / (TT * FF);   // 4096
    dim3 grid(B / RB);                        // 512 blocks, 2 per CU
    lstm2_kernel<<<grid, 256, 0, stream>>>(x, Wih0, Whh0, bih0, bhh0,
                                           Wih1, Whh1, bih1, bhh1, fcW, fcb, out);
}

// Round 2
// 3667.528 us; speedup vs baseline: 1.0069x; 1.0069x over previous
//
#include <hip/hip_runtime.h>

#define HH 50   // hidden size
#define HP 64   // padded hidden (lanes)
#define RB 8    // batch elements per block
#define TT 512  // timesteps
#define FF 4    // input features

__device__ __forceinline__ float sigm(float x)   { return 1.0f / (1.0f + __expf(-x)); }
__device__ __forceinline__ float tanh_f(float x) { return 1.0f - 2.0f / (1.0f + __expf(2.0f * x)); }

__attribute__((amdgpu_waves_per_eu(2, 2)))
__launch_bounds__(256)
__global__ void lstm2_kernel(const float* __restrict__ x,
                             const float* __restrict__ Wih0, const float* __restrict__ Whh0,
                             const float* __restrict__ bih0, const float* __restrict__ bhh0,
                             const float* __restrict__ Wih1, const float* __restrict__ Whh1,
                             const float* __restrict__ bih1, const float* __restrict__ bhh1,
                             const float* __restrict__ fcW,  const float* __restrict__ fcb,
                             float* __restrict__ out)
{
    // LDS: h-state broadcast buffers ([unit][batch], float4-readable),
    // gate exchange buffer ([gate][batch][unit], stride-1 lanes), x chunk cache.
    __shared__ __align__(16) float h0buf[HP][RB];
    __shared__ __align__(16) float h1buf[HP][RB];
    __shared__ float gbuf[4][RB][HP];
    __shared__ __align__(16) float4 xbuf[64][RB];

    const int tid = threadIdx.x;
    const int w   = tid >> 6;   // wave id = gate type (0=i,1=f,2=g,3=o)
    const int U   = tid & 63;   // lane = hidden unit (active if < 50)
    const int b0  = blockIdx.x * RB;
    // clamped row: lanes U>=50 duplicate row 49's work; their outputs land in
    // LDS slots (U>=50) that no reader ever touches.
    const int row = w * HH + (U < HH ? U : HH - 1);

    // zero h state
    for (int i = tid; i < HP * RB; i += 256) {
        (&h0buf[0][0])[i] = 0.0f;
        (&h1buf[0][0])[i] = 0.0f;
    }

    // ---- load ALL weights into registers (time-invariant, reused 512x) ----
    // vector loads (row*HH floats = row*200 B -> 8 B aligned) to keep the
    // allocator from rematerializing these into the t-loop.
    float whh0[HH], wih1[HH], whh1[HH];
    {
        const float2* p0 = (const float2*)(Whh0 + row * HH);
        const float2* p1 = (const float2*)(Wih1 + row * HH);
        const float2* p2 = (const float2*)(Whh1 + row * HH);
        #pragma unroll
        for (int j = 0; j < HH / 2; j++) {
            const float2 a = p0[j]; whh0[2 * j] = a.x; whh0[2 * j + 1] = a.y;
            const float2 b = p1[j]; wih1[2 * j] = b.x; wih1[2 * j + 1] = b.y;
            const float2 c = p2[j]; whh1[2 * j] = c.x; whh1[2 * j + 1] = c.y;
        }
    }
    const float4 w0v   = *(const float4*)(Wih0 + row * FF);  // row*16 B, aligned
    const float  bias0 = bih0[row] + bhh0[row];
    const float  bias1 = bih1[row] + bhh1[row];

    // elementwise r-slice owned by this wave
    const int r0 = 2 * w, r1 = 2 * w + 1;
    float c0a = 0.0f, c0b = 0.0f, c1a = 0.0f, c1b = 0.0f;

    __syncthreads();

    for (int t = 0; t < TT; t++) {
        // stage a 64-timestep chunk of x into LDS
        if ((t & 63) == 0) {
            __syncthreads();
            #pragma unroll
            for (int it = 0; it < 2; it++) {
                const int q  = tid + it * 256;          // [0,512)
                const int r  = q >> 6;
                const int tl = q & 63;
                xbuf[tl][r] = *(const float4*)(x + ((size_t)(b0 + r) * TT + (t + tl)) * FF);
            }
            __syncthreads();
        }

        float acc[RB];

        // ---------- layer 0 gates ----------
        #pragma unroll
        for (int r = 0; r < RB; r++) {
            const float4 xv = xbuf[t & 63][r];
            acc[r] = fmaf(w0v.x, xv.x, fmaf(w0v.y, xv.y, fmaf(w0v.z, xv.z, fmaf(w0v.w, xv.w, bias0))));
        }
        #pragma unroll
        for (int j = 0; j < HH; j++) {
            const float wj = whh0[j];
            const float4 ha = *(const float4*)&h0buf[j][0];
            const float4 hb = *(const float4*)&h0buf[j][4];
            acc[0] = fmaf(wj, ha.x, acc[0]);
            acc[1] = fmaf(wj, ha.y, acc[1]);
            acc[2] = fmaf(wj, ha.z, acc[2]);
            acc[3] = fmaf(wj, ha.w, acc[3]);
            acc[4] = fmaf(wj, hb.x, acc[4]);
            acc[5] = fmaf(wj, hb.y, acc[5]);
            acc[6] = fmaf(wj, hb.z, acc[6]);
            acc[7] = fmaf(wj, hb.w, acc[7]);
        }
        if (w == 2) {
            #pragma unroll
            for (int r = 0; r < RB; r++) gbuf[w][r][U] = tanh_f(acc[r]);
        } else {
            #pragma unroll
            for (int r = 0; r < RB; r++) gbuf[w][r][U] = sigm(acc[r]);
        }
        __syncthreads();

        // ---------- layer 0 elementwise (this wave owns r0, r1) ----------
        {
            const float i0 = gbuf[0][r0][U], f0 = gbuf[1][r0][U], g0 = gbuf[2][r0][U], o0 = gbuf[3][r0][U];
            c0a = fmaf(f0, c0a, i0 * g0);
            h0buf[U][r0] = o0 * tanh_f(c0a);
            const float i1 = gbuf[0][r1][U], f1 = gbuf[1][r1][U], g1 = gbuf[2][r1][U], o1 = gbuf[3][r1][U];
            c0b = fmaf(f1, c0b, i1 * g1);
            h0buf[U][r1] = o1 * tanh_f(c0b);
        }
        __syncthreads();

        // ---------- layer 1 gates ----------
        #pragma unroll
        for (int r = 0; r < RB; r++) acc[r] = bias1;
        #pragma unroll
        for (int j = 0; j < HH; j++) {
            const float wi = wih1[j];
            const float wh = whh1[j];
            const float4 pa = *(const float4*)&h0buf[j][0];
            const float4 pb = *(const float4*)&h0buf[j][4];
            const float4 qa = *(const float4*)&h1buf[j][0];
            const float4 qb = *(const float4*)&h1buf[j][4];
            acc[0] = fmaf(wi, pa.x, fmaf(wh, qa.x, acc[0]));
            acc[1] = fmaf(wi, pa.y, fmaf(wh, qa.y, acc[1]));
            acc[2] = fmaf(wi, pa.z, fmaf(wh, qa.z, acc[2]));
            acc[3] = fmaf(wi, pa.w, fmaf(wh, qa.w, acc[3]));
            acc[4] = fmaf(wi, pb.x, fmaf(wh, qb.x, acc[4]));
            acc[5] = fmaf(wi, pb.y, fmaf(wh, qb.y, acc[5]));
            acc[6] = fmaf(wi, pb.z, fmaf(wh, qb.z, acc[6]));
            acc[7] = fmaf(wi, pb.w, fmaf(wh, qb.w, acc[7]));
        }
        if (w == 2) {
            #pragma unroll
            for (int r = 0; r < RB; r++) gbuf[w][r][U] = tanh_f(acc[r]);
        } else {
            #pragma unroll
            for (int r = 0; r < RB; r++) gbuf[w][r][U] = sigm(acc[r]);
        }
        __syncthreads();

        // ---------- layer 1 elementwise ----------
        {
            const float i0 = gbuf[0][r0][U], f0 = gbuf[1][r0][U], g0 = gbuf[2][r0][U], o0 = gbuf[3][r0][U];
            c1a = fmaf(f0, c1a, i0 * g0);
            h1buf[U][r0] = o0 * tanh_f(c1a);
            const float i1 = gbuf[0][r1][U], f1 = gbuf[1][r1][U], g1 = gbuf[2][r1][U], o1 = gbuf[3][r1][U];
            c1b = fmaf(f1, c1b, i1 * g1);
            h1buf[U][r1] = o1 * tanh_f(c1b);
        }
        __syncthreads();
    }

    // ---------- final FC: out[b] = fcW @ h1_T + fcb ----------
    if (tid < 32) {
        const int r  = tid >> 2;
        const int ft = tid & 3;
        float s = fcb[ft];
        #pragma unroll
        for (int j = 0; j < HH; j++) s = fmaf(fcW[ft * HH + j], h1buf[j][r], s);
        out[(size_t)(b0 + r) * FF + ft] = s;
    }
}

extern "C" void kernel_launch(void* const* d_in, const int* in_sizes, int n_in,
                              void* d_out, int out_size, void* d_ws, size_t ws_size,
                              hipStream_t stream) {
    const float* x    = (const float*)d_in[0];
    const float* Wih0 = (const float*)d_in[1];
    const float* Whh0 = (const float*)d_in[2];
    const float* bih0 = (const float*)d_in[3];
    const float* bhh0 = (const float*)d_in[4];
    const float* Wih1 = (const float*)d_in[5];
    const float* Whh1 = (const float*)d_in[6];
    const float* bih1 = (const float*)d_in[7];
    const float* bhh1 = (const float*)d_in[8];
    const float* fcW  = (const float*)d_in[9];
    const float* fcb  = (const float*)d_in[10];
    float* out = (float*)d_out;

    const int B = in_sizes[0] / (TT * FF);   // 4096
    dim3 grid(B / RB);                        // 512 blocks, 2 per CU
    lstm2_kernel<<<grid, 256, 0, stream>>>(x, Wih0, Whh0, bih0, bhh0,
                                           Wih1, Whh1, bih1, bhh1, fcW, fcb, out);
}